// Round 3
// baseline (817.672 us; speedup 1.0000x reference)
//
#include <hip/hip_runtime.h>
#include <hip/hip_bf16.h>
#include <math.h>

typedef __hip_bfloat16 bf16;
typedef __bf16 bf16x8 __attribute__((ext_vector_type(8)));
typedef float f32x4 __attribute__((ext_vector_type(4)));

#define B_ 8
#define T_ 2048
#define D_ 512
#define H_ 2048

__device__ __forceinline__ float b2f(unsigned short u) {
    return __uint_as_float((unsigned)u << 16);
}
__device__ __forceinline__ float ldf(const float* p, long i) { return p[i]; }
__device__ __forceinline__ float ldf(const bf16* p, long i) {
    return b2f(((const unsigned short*)p)[i]);
}
// tanh-form gelu: v*sigmoid(1.59577(v+0.044715 v^3)); |err| < 1e-3 abs
__device__ __forceinline__ float gelu_f(float v) {
    float a = 1.5957691216057308f * (v + 0.044715f * v * v * v);
    return v / (1.0f + __expf(-a));
}

#define GLD16(g, l)                                                          \
    __builtin_amdgcn_global_load_lds(                                        \
        (const __attribute__((address_space(1))) void*)(g),                  \
        (__attribute__((address_space(3))) void*)(l), 16, 0, 0)

// LDS byte-offset of a generic pointer that actually points into LDS
__device__ __forceinline__ unsigned lds_off(const void* p) {
    return (unsigned)(unsigned long long)(const __attribute__((address_space(3))) char*)p;
}
// inline-asm ds_read_b128: invisible to the compiler's waitcnt legalizer, so it
// cannot pair it with the outstanding global_load_lds and insert vmcnt(0).
#define DSR(dst, a, OFF)                                                     \
    asm volatile("ds_read_b128 %0, %1 offset:" #OFF : "=v"(dst) : "v"(a))

// ---------------- LayerNorm over D=512, one block (256 thr) per row ----------------
template <typename Tin>
__global__ __launch_bounds__(256) void ln_kernel(const Tin* __restrict__ x,
                                                 const float* __restrict__ g,
                                                 const float* __restrict__ bb,
                                                 bf16* __restrict__ y) {
    long base = (long)blockIdx.x * D_;
    int tid = threadIdx.x;
    float v0 = ldf(x, base + tid);
    float v1 = ldf(x, base + tid + 256);
    float s = v0 + v1;
#pragma unroll
    for (int off = 32; off > 0; off >>= 1) s += __shfl_down(s, off);
    __shared__ float red[4];
    int lane = tid & 63, wid = tid >> 6;
    if (lane == 0) red[wid] = s;
    __syncthreads();
    float mean = (red[0] + red[1] + red[2] + red[3]) * (1.0f / 512.0f);
    __syncthreads();
    float d0 = v0 - mean, d1 = v1 - mean;
    float vs = d0 * d0 + d1 * d1;
#pragma unroll
    for (int off = 32; off > 0; off >>= 1) vs += __shfl_down(vs, off);
    if (lane == 0) red[wid] = vs;
    __syncthreads();
    float var = (red[0] + red[1] + red[2] + red[3]) * (1.0f / 512.0f);
    float rstd = rsqrtf(var + 1e-5f);
    y[base + tid]       = __float2bfloat16(d0 * rstd * g[tid]       + bb[tid]);
    y[base + tid + 256] = __float2bfloat16(d1 * rstd * g[tid + 256] + bb[tid + 256]);
}

// ---------------- exp(w - rowmax(w)) : one block per row of [T,T] ----------------
__global__ __launch_bounds__(256) void expw_kernel(const float* __restrict__ w,
                                                   bf16* __restrict__ ew) {
    long base = (long)blockIdx.x * T_;
    int tid = threadIdx.x;
    float v[8];
    float mx = -3.4e38f;
#pragma unroll
    for (int i = 0; i < 8; ++i) {
        v[i] = w[base + tid + i * 256];
        mx = fmaxf(mx, v[i]);
    }
#pragma unroll
    for (int off = 32; off > 0; off >>= 1) mx = fmaxf(mx, __shfl_down(mx, off));
    __shared__ float red[4];
    if ((tid & 63) == 0) red[tid >> 6] = mx;
    __syncthreads();
    float rmax = fmaxf(fmaxf(red[0], red[1]), fmaxf(red[2], red[3]));
#pragma unroll
    for (int i = 0; i < 8; ++i)
        ew[base + tid + i * 256] = __float2bfloat16(expf(v[i] - rmax));
}

// ---------------- max over batch dim of K [B,T,D] -> [T*D] (f32) ----------------
__global__ __launch_bounds__(256) void maxk_kernel(const bf16* __restrict__ K,
                                                   float* __restrict__ mk) {
    long i = (long)blockIdx.x * 256 + threadIdx.x;
    float m = ldf(K, i);
#pragma unroll
    for (int b = 1; b < B_; ++b) m = fmaxf(m, ldf(K, (long)b * (T_ * D_) + i));
    mk[i] = m;
}

// ------- build kv2T[b][n][t], n<512: expK*V (d=n); n>=512: expK (d=n-512) -------
__global__ __launch_bounds__(256) void kv2t_kernel(const bf16* __restrict__ K_,
                                                   const bf16* __restrict__ V_,
                                                   const float* __restrict__ mk,
                                                   bf16* __restrict__ kv2t) {
    __shared__ float sev[64][65];
    __shared__ float se[64][65];
    int tx = threadIdx.x & 63, ty = threadIdx.x >> 6;
    int t0 = blockIdx.x * 64, d0 = blockIdx.y * 64, b = blockIdx.z;
    long ibase = (long)b << 20;
#pragma unroll
    for (int r = 0; r < 16; ++r) {
        int tl = r * 4 + ty;
        long mi = (long)(t0 + tl) * D_ + d0 + tx;
        float e = expf(ldf(K_, ibase + mi) - mk[mi]);
        sev[tl][tx] = e * ldf(V_, ibase + mi);
        se[tl][tx] = e;
    }
    __syncthreads();
    long obase = (long)b << 21;
#pragma unroll
    for (int r = 0; r < 16; ++r) {
        int dl = r * 4 + ty;
        kv2t[obase + (long)(d0 + dl) * T_ + t0 + tx]        = __float2bfloat16(sev[tx][dl]);
        kv2t[obase + (long)(512 + d0 + dl) * T_ + t0 + tx]  = __float2bfloat16(se[tx][dl]);
    }
}

// ---------------- Yt = sigQ * num/den, in place on sigQ ----------------
__global__ __launch_bounds__(256) void yt_kernel(const bf16* __restrict__ nd,
                                                 bf16* __restrict__ q) {
    long i = (long)blockIdx.x * 256 + threadIdx.x;
    long td = i & (long)(T_ * D_ - 1);
    long b = i >> 20;
    long t = td >> 9;
    long d = td & (D_ - 1);
    long base = (b << 21) + (t << 10);
    float num = ldf(nd, base + d), den = ldf(nd, base + D_ + d);
    q[i] = __float2bfloat16(ldf(q, i) * num / den);
}

// ---------------- batched weight transpose + f32->bf16: W[K,N] -> WT[N,K] ----------
struct WT6 {
    const float* src[6];
    bf16* dst[6];
    int K[6], N[6];
};
__global__ __launch_bounds__(256) void wtrans6_kernel(WT6 p) {
    int z = blockIdx.z;
    int K = p.K[z], N = p.N[z];
    int n0 = blockIdx.x * 64, k0 = blockIdx.y * 64;
    if (n0 >= N || k0 >= K) return;
    const float* W = p.src[z];
    bf16* WT = p.dst[z];
    __shared__ float s[64][65];
    int tx = threadIdx.x & 63, ty = threadIdx.x >> 6;
#pragma unroll
    for (int r = 0; r < 16; ++r) {
        int kl = r * 4 + ty;
        s[kl][tx] = W[(long)(k0 + kl) * N + n0 + tx];
    }
    __syncthreads();
#pragma unroll
    for (int r = 0; r < 16; ++r) {
        int nl = r * 4 + ty;
        WT[(long)(n0 + nl) * K + k0 + tx] = __float2bfloat16(s[tx][nl]);
    }
}

// ---------------- MFMA GEMM: C = epi(A@Bt^T + bias) [+res] ------------------------
// BM x 128 macro-tile, 4 waves. 3-buffer LDS, depth-2 prefetch, counted vmcnt.
// Fragment loads are inline-asm ds_read_b128 (invisible to the waitcnt legalizer,
// so NO compiler vmcnt(0) is inserted — that hidden drain was the R1/R2 stall),
// followed by explicit s_waitcnt lgkmcnt(0) + sched_barrier(0) (rule #18).
// Per iter kt: vmcnt(6) [stage(kt) landed; stage(kt+1) stays in flight across the
// raw s_barrier]; s_barrier; issue stage(kt+2); asm ds_read tile kt; lgkm(0); MFMA.
// Safety: wave reaches barrier(t) only after lgkm(0) retired tile t-1's reads, so
// stage(t+2) overwriting buf((t+2)%3)==buf((t-1)%3) is race-free.
// XCD swizzle: chunked remap (nwg%8==0 for all launches here) -> A-panel readers
// share one XCD's L2 (FETCH 68->25MB measured).
// planeStride!=0: N split into 512-col planes; per-plane bias b0/b1/b2 and
// mode=(modes>>(2*plane))&3. mode 0=none 1=sigmoid 2=gelu.
template <int BM>
__global__ __launch_bounds__(256, 2) void mfma_gemm(
    const bf16* __restrict__ A, const bf16* __restrict__ Bt,
    const float* __restrict__ b0, const float* __restrict__ b1,
    const float* __restrict__ b2,
    bf16* __restrict__ Cb, float* __restrict__ Cf,
    const bf16* __restrict__ resb, const float* __restrict__ resf,
    int M, int N, int K, int modes, long bsB, long bsC, long planeStride) {
    constexpr int MI = BM / 32;
    constexpr int NA = BM / 64;
    constexpr int PL = (BM + 128) * 32;   // shorts per LDS buffer plane
    constexpr unsigned PLB = PL * 2;      // bytes per plane
    __shared__ short Sh[3 * PL];          // 3 bufs: 72KB (BM=256) / 48KB (BM=128)
    int tid = threadIdx.x;
    int lane = tid & 63, wave = tid >> 6;
    int wm = wave & 1, wn = wave >> 1;

    // chunked XCD swizzle on the (x,y) grid; per-z slice (nwg % 8 == 0 always here)
    int gx = gridDim.x;
    int nwg = gx * gridDim.y;
    int o = blockIdx.x + gx * blockIdx.y;
    int wk = (o & 7) * (nwg >> 3) + (o >> 3);
    int bx = wk % gx, by = wk / gx;
    int m0 = by * BM, n0 = bx * 128;

    const short* Ag = (const short*)A;
    const short* Bg = (const short*)Bt + (long)blockIdx.z * bsB;

    int lr = lane >> 2;
    int le = (lane & 3) * 8;
    const short* ga[NA];
    short* la[NA];
#pragma unroll
    for (int i = 0; i < NA; ++i) {
        ga[i] = Ag + (long)(m0 + wave * (BM / 4) + i * 16 + lr) * K + le;
        la[i] = Sh + (wave * (BM / 4) + i * 16) * 32;
    }
    const short* gb0 = Bg + (long)(n0 + wave * 32 + lr) * K + le;
    const short* gb1 = gb0 + 16L * K;
    short* lb0 = Sh + BM * 32 + (wave * 32) * 32;
    short* lb1 = lb0 + 16 * 32;

    f32x4 acc[MI][4];
    f32x4 zz = {0.f, 0.f, 0.f, 0.f};
#pragma unroll
    for (int i = 0; i < MI; ++i)
#pragma unroll
        for (int j = 0; j < 4; ++j) acc[i][j] = zz;

    int fr = lane & 15;
    int fk = (lane >> 4) * 8;
    int rm = wm * (BM / 2);

    // per-wave LDS fragment base byte-offsets (A rows 64B; B region at BM*64 bytes)
    unsigned aBase = lds_off(Sh) + (unsigned)((rm + fr) * 64 + fk * 2);
    unsigned bBase = lds_off(Sh) + (unsigned)(BM * 64 + (wn * 64 + fr) * 64 + fk * 2);

    auto stage = [&](int kt, int bi) {
        int ko = kt * 32;
        int ofs = bi * PL;
#pragma unroll
        for (int i = 0; i < NA; ++i) GLD16(ga[i] + ko, la[i] + ofs);
        GLD16(gb0 + ko, lb0 + ofs);
        GLD16(gb1 + ko, lb1 + ofs);
    };
    auto compute = [&](int bi) {
        unsigned ab = aBase + (unsigned)bi * PLB;
        unsigned bb2 = bBase + (unsigned)bi * PLB;
        bf16x8 af[MI], bv[4];
        DSR(af[0], ab, 0);
        DSR(af[1], ab, 1024);
        DSR(af[2], ab, 2048);
        DSR(af[3], ab, 3072);
        if constexpr (MI == 8) {
            DSR(af[4], ab, 4096);
            DSR(af[5], ab, 5120);
            DSR(af[6], ab, 6144);
            DSR(af[7], ab, 7168);
        }
        DSR(bv[0], bb2, 0);
        DSR(bv[1], bb2, 1024);
        DSR(bv[2], bb2, 2048);
        DSR(bv[3], bb2, 3072);
        asm volatile("s_waitcnt lgkmcnt(0)" ::: "memory");
        __builtin_amdgcn_sched_barrier(0);
#pragma unroll
        for (int mi = 0; mi < MI; ++mi)
#pragma unroll
            for (int ni = 0; ni < 4; ++ni)
                acc[mi][ni] = __builtin_amdgcn_mfma_f32_16x16x32_bf16(
                    af[mi], bv[ni], acc[mi][ni], 0, 0, 0);
    };

    // ---- depth-2 pipelined K loop, counted vmcnt (NA+2 loads per stage/wave) ----
    int nk = K >> 5;
    stage(0, 0);
    stage(1, 1);
    int bi = 0;
    for (int kt = 0; kt < nk; ++kt) {
        if (kt + 1 < nk) {
            if constexpr (BM == 256)
                asm volatile("s_waitcnt vmcnt(6)" ::: "memory");
            else
                asm volatile("s_waitcnt vmcnt(4)" ::: "memory");
        } else {
            asm volatile("s_waitcnt vmcnt(0)" ::: "memory");
        }
        __builtin_amdgcn_s_barrier();
        if (kt + 2 < nk) stage(kt + 2, bi == 0 ? 2 : bi - 1);
        compute(bi);
        bi = (bi == 2) ? 0 : bi + 1;
    }

    int cc = lane & 15, cr = (lane >> 4) * 4;
    long cbase = (long)blockIdx.z * bsC;
#pragma unroll
    for (int mi = 0; mi < MI; ++mi) {
#pragma unroll
        for (int ni = 0; ni < 4; ++ni) {
            int row0 = m0 + rm + mi * 16 + cr;
            int col = n0 + wn * 64 + ni * 16 + cc;
            float bvl;
            long colterm;
            int md, rowstride;
            if (planeStride) {
                int plane = col >> 9;
                int c2 = col & 511;
                const float* bp = (plane == 0) ? b0 : ((plane == 1) ? b1 : b2);
                bvl = bp[c2];
                md = (modes >> (2 * plane)) & 3;
                colterm = (long)plane * planeStride + c2;
                rowstride = 512;
            } else {
                bvl = b0 ? b0[col] : 0.0f;
                md = modes & 3;
                colterm = col;
                rowstride = N;
            }
#pragma unroll
            for (int r = 0; r < 4; ++r) {
                float v = acc[mi][ni][r] + bvl;
                if (md == 1) v = 1.0f / (1.0f + __expf(-v));
                else if (md == 2) v = gelu_f(v);
                long idx = cbase + (long)(row0 + r) * rowstride + colterm;
                if (resf) v += resf[idx];
                if (resb) v += ldf(resb, idx);
                if (Cf) Cf[idx] = v;
                else Cb[idx] = __float2bfloat16(v);
            }
        }
    }
}

extern "C" void kernel_launch(void* const* d_in, const int* in_sizes, int n_in,
                              void* d_out, int out_size, void* d_ws, size_t ws_size,
                              hipStream_t stream) {
    const float* x    = (const float*)d_in[0];
    const float* ln1g = (const float*)d_in[1];
    const float* ln1b = (const float*)d_in[2];
    const float* Wk   = (const float*)d_in[3];
    const float* bk   = (const float*)d_in[4];
    const float* Wv   = (const float*)d_in[5];
    const float* bv   = (const float*)d_in[6];
    const float* Wq   = (const float*)d_in[7];
    const float* bq   = (const float*)d_in[8];
    const float* w    = (const float*)d_in[9];
    const float* Wo   = (const float*)d_in[10];
    const float* bo   = (const float*)d_in[11];
    const float* ln2g = (const float*)d_in[12];
    const float* ln2b = (const float*)d_in[13];
    const float* W1   = (const float*)d_in[14];
    const float* b1   = (const float*)d_in[15];
    const float* W2   = (const float*)d_in[16];
    const float* b2   = (const float*)d_in[17];
    float* out = (float*)d_out;

    const long S_BTD = (long)B_ * T_ * D_;      // 8,388,608
    const long S_TD  = (long)T_ * D_;           // 1,048,576
    const long S_TT  = (long)T_ * T_;           // 4,194,304
    const long S_B2D = (long)B_ * T_ * 2 * D_;  // 16,777,216
    const long S_DD  = (long)D_ * D_;           // 262,144

    // Workspace (bf16 elems unless noted) ~136 MB:
    bf16* h1     = (bf16*)d_ws;            // later h2
    bf16* outres = h1 + S_BTD;
    bf16* ew     = outres + S_BTD;
    bf16* KVQ    = ew + S_TT;              // K|V|Q planes (3*S_BTD)
    bf16* kv2t   = KVQ + 3 * S_BTD;        // S_B2D
    float* mk    = (float*)(kv2t + S_B2D); // S_TD f32
    bf16* WkT    = (bf16*)(mk + S_TD);
    bf16* WvT    = WkT + S_DD;
    bf16* WqT    = WvT + S_DD;
    bf16* WoT    = WqT + S_DD;
    bf16* W1T    = WoT + S_DD;             // [H,D]
    bf16* W2T    = W1T + (long)D_ * H_;    // [D,H]
    bf16* Kb  = KVQ;
    bf16* Vb  = KVQ + S_BTD;
    bf16* Qb  = KVQ + 2 * S_BTD;           // sigQ, then Yt in place
    bf16* nd  = KVQ;                       // overwrites K|V planes after kv2t
    bf16* hH  = KVQ;                       // spans KVQ(24M)+kv2t(16M) >= 33.6M elems
    bf16* h2  = h1;

    const int M = B_ * T_;  // 16384

    // 1. batched weight transposes
    WT6 p;
    p.src[0] = Wk; p.src[1] = Wv; p.src[2] = Wq; p.src[3] = Wo; p.src[4] = W1; p.src[5] = W2;
    p.dst[0] = WkT; p.dst[1] = WvT; p.dst[2] = WqT; p.dst[3] = WoT; p.dst[4] = W1T; p.dst[5] = W2T;
    p.K[0] = p.K[1] = p.K[2] = p.K[3] = 512; p.K[4] = 512; p.K[5] = 2048;
    p.N[0] = p.N[1] = p.N[2] = p.N[3] = 512; p.N[4] = 2048; p.N[5] = 512;
    wtrans6_kernel<<<dim3(32, 32, 6), 256, 0, stream>>>(p);
    // 2. h1 = LN1(x)
    ln_kernel<float><<<M, 256, 0, stream>>>(x, ln1g, ln1b, h1);
    // 3. K|V|sigQ GEMM: N=1536 over [WkT;WvT;WqT], 3 planes -> Kb,Vb,Qb
    mfma_gemm<256><<<dim3(1536 / 128, M / 256, 1), 256, 0, stream>>>(
        h1, WkT, bk, bv, bq, Kb, nullptr, nullptr, nullptr,
        M, 1536, D_, (1 << 4), 0, 0, S_BTD);
    // 4. mk = max_b K; 5. kv2t = [expK*V | expK]^T per batch
    maxk_kernel<<<S_TD / 256, 256, 0, stream>>>(Kb, mk);
    kv2t_kernel<<<dim3(T_ / 64, D_ / 64, B_), 256, 0, stream>>>(Kb, Vb, mk, kv2t);
    // 6. exp_w
    expw_kernel<<<T_, 256, 0, stream>>>(w, ew);
    // 7. nd[b] = ew @ kv2t[b]^T  (M=2048, N=1024, K=2048) — overwrites K|V planes
    mfma_gemm<256><<<dim3(1024 / 128, T_ / 256, B_), 256, 0, stream>>>(
        ew, kv2t, nullptr, nullptr, nullptr, nd, nullptr, nullptr, nullptr,
        T_, 1024, T_, 0, (long)1024 * T_, (long)T_ * 1024, 0);
    // 8. Yt = sigQ * num/den (in place on Qb)
    yt_kernel<<<S_BTD / 256, 256, 0, stream>>>(nd, Qb);
    // 9. out = Yt@Wo + bo + x
    mfma_gemm<128><<<dim3(D_ / 128, M / 128, 1), 256, 0, stream>>>(
        Qb, WoT, bo, nullptr, nullptr, outres, nullptr, nullptr, x,
        M, D_, D_, 0, 0, 0, 0);
    // 10. h2 = LN2(out)
    ln_kernel<bf16><<<M, 256, 0, stream>>>(outres, ln2g, ln2b, h2);
    // 11. hH = gelu(h2@W1 + b1)  (overwrites KVQ/kv2t span)
    mfma_gemm<256><<<dim3(H_ / 128, M / 256, 1), 256, 0, stream>>>(
        h2, W1T, b1, nullptr, nullptr, hH, nullptr, nullptr, nullptr,
        M, H_, D_, 2, 0, 0, 0);
    // 12. y = gelu(hH@W2 + b2) + out -> f32 d_out
    mfma_gemm<128><<<dim3(D_ / 128, M / 128, 1), 256, 0, stream>>>(
        hH, W2T, b2, nullptr, nullptr, nullptr, out, outres, nullptr,
        M, D_, H_, 2, 0, 0, 0);
}

// Round 4
// 504.901 us; speedup vs baseline: 1.6195x; 1.6195x over previous
//
#include <hip/hip_runtime.h>
#include <hip/hip_bf16.h>
#include <math.h>

typedef __hip_bfloat16 bf16;
typedef __bf16 bf16x8 __attribute__((ext_vector_type(8)));
typedef float f32x4 __attribute__((ext_vector_type(4)));

#define B_ 8
#define T_ 2048
#define D_ 512
#define H_ 2048

__device__ __forceinline__ float b2f(unsigned short u) {
    return __uint_as_float((unsigned)u << 16);
}
__device__ __forceinline__ float ldf(const float* p, long i) { return p[i]; }
__device__ __forceinline__ float ldf(const bf16* p, long i) {
    return b2f(((const unsigned short*)p)[i]);
}
// tanh-form gelu: v*sigmoid(1.59577(v+0.044715 v^3)); |err| < 1e-3 abs
__device__ __forceinline__ float gelu_f(float v) {
    float a = 1.5957691216057308f * (v + 0.044715f * v * v * v);
    return v / (1.0f + __expf(-a));
}

#define GLD16(g, l)                                                          \
    __builtin_amdgcn_global_load_lds(                                        \
        (const __attribute__((address_space(1))) void*)(g),                  \
        (__attribute__((address_space(3))) void*)(l), 16, 0, 0)

// ---------------- LayerNorm over D=512, one block (256 thr) per row ----------------
template <typename Tin>
__global__ __launch_bounds__(256) void ln_kernel(const Tin* __restrict__ x,
                                                 const float* __restrict__ g,
                                                 const float* __restrict__ bb,
                                                 bf16* __restrict__ y) {
    long base = (long)blockIdx.x * D_;
    int tid = threadIdx.x;
    float v0 = ldf(x, base + tid);
    float v1 = ldf(x, base + tid + 256);
    float s = v0 + v1;
#pragma unroll
    for (int off = 32; off > 0; off >>= 1) s += __shfl_down(s, off);
    __shared__ float red[4];
    int lane = tid & 63, wid = tid >> 6;
    if (lane == 0) red[wid] = s;
    __syncthreads();
    float mean = (red[0] + red[1] + red[2] + red[3]) * (1.0f / 512.0f);
    __syncthreads();
    float d0 = v0 - mean, d1 = v1 - mean;
    float vs = d0 * d0 + d1 * d1;
#pragma unroll
    for (int off = 32; off > 0; off >>= 1) vs += __shfl_down(vs, off);
    if (lane == 0) red[wid] = vs;
    __syncthreads();
    float var = (red[0] + red[1] + red[2] + red[3]) * (1.0f / 512.0f);
    float rstd = rsqrtf(var + 1e-5f);
    y[base + tid]       = __float2bfloat16(d0 * rstd * g[tid]       + bb[tid]);
    y[base + tid + 256] = __float2bfloat16(d1 * rstd * g[tid + 256] + bb[tid + 256]);
}

// ---------------- exp(w - rowmax(w)) : one block per row of [T,T] ----------------
__global__ __launch_bounds__(256) void expw_kernel(const float* __restrict__ w,
                                                   bf16* __restrict__ ew) {
    long base = (long)blockIdx.x * T_;
    int tid = threadIdx.x;
    float v[8];
    float mx = -3.4e38f;
#pragma unroll
    for (int i = 0; i < 8; ++i) {
        v[i] = w[base + tid + i * 256];
        mx = fmaxf(mx, v[i]);
    }
#pragma unroll
    for (int off = 32; off > 0; off >>= 1) mx = fmaxf(mx, __shfl_down(mx, off));
    __shared__ float red[4];
    if ((tid & 63) == 0) red[tid >> 6] = mx;
    __syncthreads();
    float rmax = fmaxf(fmaxf(red[0], red[1]), fmaxf(red[2], red[3]));
#pragma unroll
    for (int i = 0; i < 8; ++i)
        ew[base + tid + i * 256] = __float2bfloat16(expf(v[i] - rmax));
}

// ---------------- max over batch dim of K [B,T,D] -> [T*D] (f32) ----------------
__global__ __launch_bounds__(256) void maxk_kernel(const bf16* __restrict__ K,
                                                   float* __restrict__ mk) {
    long i = (long)blockIdx.x * 256 + threadIdx.x;
    float m = ldf(K, i);
#pragma unroll
    for (int b = 1; b < B_; ++b) m = fmaxf(m, ldf(K, (long)b * (T_ * D_) + i));
    mk[i] = m;
}

// ------- build kv2T[b][n][t], n<512: expK*V (d=n); n>=512: expK (d=n-512) -------
__global__ __launch_bounds__(256) void kv2t_kernel(const bf16* __restrict__ K_,
                                                   const bf16* __restrict__ V_,
                                                   const float* __restrict__ mk,
                                                   bf16* __restrict__ kv2t) {
    __shared__ float sev[64][65];
    __shared__ float se[64][65];
    int tx = threadIdx.x & 63, ty = threadIdx.x >> 6;
    int t0 = blockIdx.x * 64, d0 = blockIdx.y * 64, b = blockIdx.z;
    long ibase = (long)b << 20;
#pragma unroll
    for (int r = 0; r < 16; ++r) {
        int tl = r * 4 + ty;
        long mi = (long)(t0 + tl) * D_ + d0 + tx;
        float e = expf(ldf(K_, ibase + mi) - mk[mi]);
        sev[tl][tx] = e * ldf(V_, ibase + mi);
        se[tl][tx] = e;
    }
    __syncthreads();
    long obase = (long)b << 21;
#pragma unroll
    for (int r = 0; r < 16; ++r) {
        int dl = r * 4 + ty;
        kv2t[obase + (long)(d0 + dl) * T_ + t0 + tx]        = __float2bfloat16(sev[tx][dl]);
        kv2t[obase + (long)(512 + d0 + dl) * T_ + t0 + tx]  = __float2bfloat16(se[tx][dl]);
    }
}

// ---------------- Yt = sigQ * num/den, in place on sigQ ----------------
__global__ __launch_bounds__(256) void yt_kernel(const bf16* __restrict__ nd,
                                                 bf16* __restrict__ q) {
    long i = (long)blockIdx.x * 256 + threadIdx.x;
    long td = i & (long)(T_ * D_ - 1);
    long b = i >> 20;
    long t = td >> 9;
    long d = td & (D_ - 1);
    long base = (b << 21) + (t << 10);
    float num = ldf(nd, base + d), den = ldf(nd, base + D_ + d);
    q[i] = __float2bfloat16(ldf(q, i) * num / den);
}

// ---------------- batched weight transpose + f32->bf16: W[K,N] -> WT[N,K] ----------
struct WT6 {
    const float* src[6];
    bf16* dst[6];
    int K[6], N[6];
};
__global__ __launch_bounds__(256) void wtrans6_kernel(WT6 p) {
    int z = blockIdx.z;
    int K = p.K[z], N = p.N[z];
    int n0 = blockIdx.x * 64, k0 = blockIdx.y * 64;
    if (n0 >= N || k0 >= K) return;
    const float* W = p.src[z];
    bf16* WT = p.dst[z];
    __shared__ float s[64][65];
    int tx = threadIdx.x & 63, ty = threadIdx.x >> 6;
#pragma unroll
    for (int r = 0; r < 16; ++r) {
        int kl = r * 4 + ty;
        s[kl][tx] = W[(long)(k0 + kl) * N + n0 + tx];
    }
    __syncthreads();
#pragma unroll
    for (int r = 0; r < 16; ++r) {
        int nl = r * 4 + ty;
        WT[(long)(n0 + nl) * K + k0 + tx] = __float2bfloat16(s[tx][nl]);
    }
}

// ---------------- MFMA GEMM: C = epi(A@Bt^T + bias) [+res] ------------------------
// 128 x 128 macro-tile (m97-proven shape), 4 waves, 2-buffer LDS, plain C++ LDS
// reads (compiler-managed fine-grained lgkmcnt), __syncthreads per K-step.
// WHY 128 and not 256: BM=256 carries 128 f32 acc/thread in AGPRs -> ~220 unified
// regs/wave -> 2 waves/SIMD -> 2 blocks/CU (measured Occ 21%) -> nothing covers the
// vmcnt(0) barrier drain. BM=128: 64 acc -> ~156 regs -> 3 blocks/CU; m114 shows
// implicit multi-block overlap is what hides the drain (m97: 874 TF this way).
// XCD swizzle: chunked remap (nwg%8==0 for all launches) -> A-panel readers share
// one XCD's L2 (FETCH 68->25MB measured in R2).
// planeStride!=0: N split into 512-col planes; per-plane bias b0/b1/b2 and
// mode=(modes>>(2*plane))&3. mode 0=none 1=sigmoid 2=gelu.
template <int BM>
__global__ __launch_bounds__(256, 3) void mfma_gemm(
    const bf16* __restrict__ A, const bf16* __restrict__ Bt,
    const float* __restrict__ b0, const float* __restrict__ b1,
    const float* __restrict__ b2,
    bf16* __restrict__ Cb, float* __restrict__ Cf,
    const bf16* __restrict__ resb, const float* __restrict__ resf,
    int M, int N, int K, int modes, long bsB, long bsC, long planeStride) {
    constexpr int MI = BM / 32;
    constexpr int NA = BM / 64;
    constexpr int PL = (BM + 128) * 32;  // shorts per LDS buffer plane
    __shared__ short Sh[2 * PL];         // 2 bufs: 32KB @BM=128
    int tid = threadIdx.x;
    int lane = tid & 63, wave = tid >> 6;
    int wm = wave & 1, wn = wave >> 1;

    // chunked XCD swizzle on the (x,y) grid; per-z slice (nwg % 8 == 0 always here)
    int gx = gridDim.x;
    int nwg = gx * gridDim.y;
    int o = blockIdx.x + gx * blockIdx.y;
    int wk = (o & 7) * (nwg >> 3) + (o >> 3);
    int bx = wk % gx, by = wk / gx;
    int m0 = by * BM, n0 = bx * 128;

    const short* Ag = (const short*)A;
    const short* Bg = (const short*)Bt + (long)blockIdx.z * bsB;

    int lr = lane >> 2;
    int le = (lane & 3) * 8;
    const short* ga[NA];
    short* la[NA];
#pragma unroll
    for (int i = 0; i < NA; ++i) {
        ga[i] = Ag + (long)(m0 + wave * (BM / 4) + i * 16 + lr) * K + le;
        la[i] = Sh + (wave * (BM / 4) + i * 16) * 32;
    }
    const short* gb0 = Bg + (long)(n0 + wave * 32 + lr) * K + le;
    const short* gb1 = gb0 + 16L * K;
    short* lb0 = Sh + BM * 32 + (wave * 32) * 32;
    short* lb1 = lb0 + 16 * 32;

    f32x4 acc[MI][4];
    f32x4 zz = {0.f, 0.f, 0.f, 0.f};
#pragma unroll
    for (int i = 0; i < MI; ++i)
#pragma unroll
        for (int j = 0; j < 4; ++j) acc[i][j] = zz;

    int fr = lane & 15;
    int fk = (lane >> 4) * 8;
    int rm = wm * (BM / 2);

    auto stage = [&](int kt, int ofs) {
        int ko = kt * 32;
#pragma unroll
        for (int i = 0; i < NA; ++i) GLD16(ga[i] + ko, la[i] + ofs);
        GLD16(gb0 + ko, lb0 + ofs);
        GLD16(gb1 + ko, lb1 + ofs);
    };
    auto compute = [&](int ofs) {
        const short* Asb = Sh + ofs;
        const short* Bsb = Sh + ofs + BM * 32;
        bf16x8 af[MI], bv[4];
#pragma unroll
        for (int mi = 0; mi < MI; ++mi)
            af[mi] = *(const bf16x8*)(Asb + (rm + mi * 16 + fr) * 32 + fk);
#pragma unroll
        for (int ni = 0; ni < 4; ++ni)
            bv[ni] = *(const bf16x8*)(Bsb + (wn * 64 + ni * 16 + fr) * 32 + fk);
#pragma unroll
        for (int mi = 0; mi < MI; ++mi)
#pragma unroll
            for (int ni = 0; ni < 4; ++ni)
                acc[mi][ni] = __builtin_amdgcn_mfma_f32_16x16x32_bf16(
                    af[mi], bv[ni], acc[mi][ni], 0, 0, 0);
    };

    // ---- 2-buffer pipelined K loop (nk even for all shapes used: K=512/2048) ----
    int nk = K >> 5;
    stage(0, 0);
    __syncthreads();
    for (int kt = 0; kt < nk; kt += 2) {
        if (kt + 1 < nk) stage(kt + 1, PL);
        compute(0);
        __syncthreads();
        if (kt + 2 < nk) stage(kt + 2, 0);
        compute(PL);
        __syncthreads();
    }

    int cc = lane & 15, cr = (lane >> 4) * 4;
    long cbase = (long)blockIdx.z * bsC;
#pragma unroll
    for (int mi = 0; mi < MI; ++mi) {
#pragma unroll
        for (int ni = 0; ni < 4; ++ni) {
            int row0 = m0 + rm + mi * 16 + cr;
            int col = n0 + wn * 64 + ni * 16 + cc;
            float bvl;
            long colterm;
            int md, rowstride;
            if (planeStride) {
                int plane = col >> 9;
                int c2 = col & 511;
                const float* bp = (plane == 0) ? b0 : ((plane == 1) ? b1 : b2);
                bvl = bp[c2];
                md = (modes >> (2 * plane)) & 3;
                colterm = (long)plane * planeStride + c2;
                rowstride = 512;
            } else {
                bvl = b0 ? b0[col] : 0.0f;
                md = modes & 3;
                colterm = col;
                rowstride = N;
            }
#pragma unroll
            for (int r = 0; r < 4; ++r) {
                float v = acc[mi][ni][r] + bvl;
                if (md == 1) v = 1.0f / (1.0f + __expf(-v));
                else if (md == 2) v = gelu_f(v);
                long idx = cbase + (long)(row0 + r) * rowstride + colterm;
                if (resf) v += resf[idx];
                if (resb) v += ldf(resb, idx);
                if (Cf) Cf[idx] = v;
                else Cb[idx] = __float2bfloat16(v);
            }
        }
    }
}

extern "C" void kernel_launch(void* const* d_in, const int* in_sizes, int n_in,
                              void* d_out, int out_size, void* d_ws, size_t ws_size,
                              hipStream_t stream) {
    const float* x    = (const float*)d_in[0];
    const float* ln1g = (const float*)d_in[1];
    const float* ln1b = (const float*)d_in[2];
    const float* Wk   = (const float*)d_in[3];
    const float* bk   = (const float*)d_in[4];
    const float* Wv   = (const float*)d_in[5];
    const float* bv   = (const float*)d_in[6];
    const float* Wq   = (const float*)d_in[7];
    const float* bq   = (const float*)d_in[8];
    const float* w    = (const float*)d_in[9];
    const float* Wo   = (const float*)d_in[10];
    const float* bo   = (const float*)d_in[11];
    const float* ln2g = (const float*)d_in[12];
    const float* ln2b = (const float*)d_in[13];
    const float* W1   = (const float*)d_in[14];
    const float* b1   = (const float*)d_in[15];
    const float* W2   = (const float*)d_in[16];
    const float* b2   = (const float*)d_in[17];
    float* out = (float*)d_out;

    const long S_BTD = (long)B_ * T_ * D_;      // 8,388,608
    const long S_TD  = (long)T_ * D_;           // 1,048,576
    const long S_TT  = (long)T_ * T_;           // 4,194,304
    const long S_B2D = (long)B_ * T_ * 2 * D_;  // 16,777,216
    const long S_DD  = (long)D_ * D_;           // 262,144

    // Workspace (bf16 elems unless noted) ~136 MB:
    bf16* h1     = (bf16*)d_ws;            // later h2
    bf16* outres = h1 + S_BTD;
    bf16* ew     = outres + S_BTD;
    bf16* KVQ    = ew + S_TT;              // K|V|Q planes (3*S_BTD)
    bf16* kv2t   = KVQ + 3 * S_BTD;        // S_B2D
    float* mk    = (float*)(kv2t + S_B2D); // S_TD f32
    bf16* WkT    = (bf16*)(mk + S_TD);
    bf16* WvT    = WkT + S_DD;
    bf16* WqT    = WvT + S_DD;
    bf16* WoT    = WqT + S_DD;
    bf16* W1T    = WoT + S_DD;             // [H,D]
    bf16* W2T    = W1T + (long)D_ * H_;    // [D,H]
    bf16* Kb  = KVQ;
    bf16* Vb  = KVQ + S_BTD;
    bf16* Qb  = KVQ + 2 * S_BTD;           // sigQ, then Yt in place
    bf16* nd  = KVQ;                       // overwrites K|V planes after kv2t
    bf16* hH  = KVQ;                       // spans KVQ(24M)+kv2t(16M) >= 33.6M elems
    bf16* h2  = h1;

    const int M = B_ * T_;  // 16384

    // 1. batched weight transposes
    WT6 p;
    p.src[0] = Wk; p.src[1] = Wv; p.src[2] = Wq; p.src[3] = Wo; p.src[4] = W1; p.src[5] = W2;
    p.dst[0] = WkT; p.dst[1] = WvT; p.dst[2] = WqT; p.dst[3] = WoT; p.dst[4] = W1T; p.dst[5] = W2T;
    p.K[0] = p.K[1] = p.K[2] = p.K[3] = 512; p.K[4] = 512; p.K[5] = 2048;
    p.N[0] = p.N[1] = p.N[2] = p.N[3] = 512; p.N[4] = 2048; p.N[5] = 512;
    wtrans6_kernel<<<dim3(32, 32, 6), 256, 0, stream>>>(p);
    // 2. h1 = LN1(x)
    ln_kernel<float><<<M, 256, 0, stream>>>(x, ln1g, ln1b, h1);
    // 3. K|V|sigQ GEMM: N=1536 over [WkT;WvT;WqT], 3 planes -> Kb,Vb,Qb
    mfma_gemm<128><<<dim3(1536 / 128, M / 128, 1), 256, 0, stream>>>(
        h1, WkT, bk, bv, bq, Kb, nullptr, nullptr, nullptr,
        M, 1536, D_, (1 << 4), 0, 0, S_BTD);
    // 4. mk = max_b K; 5. kv2t = [expK*V | expK]^T per batch
    maxk_kernel<<<S_TD / 256, 256, 0, stream>>>(Kb, mk);
    kv2t_kernel<<<dim3(T_ / 64, D_ / 64, B_), 256, 0, stream>>>(Kb, Vb, mk, kv2t);
    // 6. exp_w
    expw_kernel<<<T_, 256, 0, stream>>>(w, ew);
    // 7. nd[b] = ew @ kv2t[b]^T  (M=2048, N=1024, K=2048) — overwrites K|V planes
    mfma_gemm<128><<<dim3(1024 / 128, T_ / 128, B_), 256, 0, stream>>>(
        ew, kv2t, nullptr, nullptr, nullptr, nd, nullptr, nullptr, nullptr,
        T_, 1024, T_, 0, (long)1024 * T_, (long)T_ * 1024, 0);
    // 8. Yt = sigQ * num/den (in place on Qb)
    yt_kernel<<<S_BTD / 256, 256, 0, stream>>>(nd, Qb);
    // 9. out = Yt@Wo + bo + x
    mfma_gemm<128><<<dim3(D_ / 128, M / 128, 1), 256, 0, stream>>>(
        Qb, WoT, bo, nullptr, nullptr, outres, nullptr, nullptr, x,
        M, D_, D_, 0, 0, 0, 0);
    // 10. h2 = LN2(out)
    ln_kernel<bf16><<<M, 256, 0, stream>>>(outres, ln2g, ln2b, h2);
    // 11. hH = gelu(h2@W1 + b1)  (overwrites KVQ/kv2t span)
    mfma_gemm<128><<<dim3(H_ / 128, M / 128, 1), 256, 0, stream>>>(
        h2, W1T, b1, nullptr, nullptr, hH, nullptr, nullptr, nullptr,
        M, H_, D_, 2, 0, 0, 0);
    // 12. y = gelu(hH@W2 + b2) + out -> f32 d_out
    mfma_gemm<128><<<dim3(D_ / 128, M / 128, 1), 256, 0, stream>>>(
        hH, W2T, b2, nullptr, nullptr, nullptr, out, outres, nullptr,
        M, D_, H_, 2, 0, 0, 0);
}

// Round 5
// 490.094 us; speedup vs baseline: 1.6684x; 1.0302x over previous
//
#include <hip/hip_runtime.h>
#include <hip/hip_bf16.h>
#include <math.h>

typedef __hip_bfloat16 bf16;
typedef __bf16 bf16x8 __attribute__((ext_vector_type(8)));
typedef float f32x4 __attribute__((ext_vector_type(4)));

#define B_ 8
#define T_ 2048
#define D_ 512
#define H_ 2048

__device__ __forceinline__ float b2f(unsigned short u) {
    return __uint_as_float((unsigned)u << 16);
}
__device__ __forceinline__ float ldf(const float* p, long i) { return p[i]; }
__device__ __forceinline__ float ldf(const bf16* p, long i) {
    return b2f(((const unsigned short*)p)[i]);
}
// tanh-form gelu: v*sigmoid(1.59577(v+0.044715 v^3)); |err| < 1e-3 abs
__device__ __forceinline__ float gelu_f(float v) {
    float a = 1.5957691216057308f * (v + 0.044715f * v * v * v);
    return v / (1.0f + __expf(-a));
}

// Packed (tile-major) layout for GEMM-staged operands:
// tile = 16 rows x 32 cols (1 KB bf16) = exactly one wave's global_load_lds
// payload in LDS dest order: within-tile offset = (row&15)*32 + (col&31).
// tiles ordered (row-tile-major, then k-tile):
//   off(row,col,K) = ((row>>4)*(K>>5) + (col>>5))*512 + (row&15)*32 + (col&31)
// => staging becomes fully-contiguous 1KB bursts (8 full 128B lines) instead of
// 16 x 64B segments at 4KB stride (which inflated FETCH 1.7x, R4 = 138MB).
__device__ __forceinline__ long poff(int row, int col, int K) {
    return ((long)(row >> 4) * (K >> 5) + (col >> 5)) * 512 + (row & 15) * 32 + (col & 31);
}

#define GLD16(g, l)                                                          \
    __builtin_amdgcn_global_load_lds(                                        \
        (const __attribute__((address_space(1))) void*)(g),                  \
        (__attribute__((address_space(3))) void*)(l), 16, 0, 0)

// ---------------- LayerNorm over D=512, one block (256 thr) per row ----------------
// PACKO: emit y in packed tile layout (consumed only by GEMM staging)
template <typename Tin, bool PACKO>
__global__ __launch_bounds__(256) void ln_kernel(const Tin* __restrict__ x,
                                                 const float* __restrict__ g,
                                                 const float* __restrict__ bb,
                                                 bf16* __restrict__ y) {
    int row = blockIdx.x;
    long base = (long)row * D_;
    int tid = threadIdx.x;
    float v0 = ldf(x, base + tid);
    float v1 = ldf(x, base + tid + 256);
    float s = v0 + v1;
#pragma unroll
    for (int off = 32; off > 0; off >>= 1) s += __shfl_down(s, off);
    __shared__ float red[4];
    int lane = tid & 63, wid = tid >> 6;
    if (lane == 0) red[wid] = s;
    __syncthreads();
    float mean = (red[0] + red[1] + red[2] + red[3]) * (1.0f / 512.0f);
    __syncthreads();
    float d0 = v0 - mean, d1 = v1 - mean;
    float vs = d0 * d0 + d1 * d1;
#pragma unroll
    for (int off = 32; off > 0; off >>= 1) vs += __shfl_down(vs, off);
    if (lane == 0) red[wid] = vs;
    __syncthreads();
    float var = (red[0] + red[1] + red[2] + red[3]) * (1.0f / 512.0f);
    float rstd = rsqrtf(var + 1e-5f);
    float o0 = d0 * rstd * g[tid] + bb[tid];
    float o1 = d1 * rstd * g[tid + 256] + bb[tid + 256];
    if (PACKO) {
        y[poff(row, tid, D_)]       = __float2bfloat16(o0);
        y[poff(row, tid + 256, D_)] = __float2bfloat16(o1);
    } else {
        y[base + tid]       = __float2bfloat16(o0);
        y[base + tid + 256] = __float2bfloat16(o1);
    }
}

// ---------------- exp(w - rowmax(w)) : one block per row; PACKED output ----------
__global__ __launch_bounds__(256) void expw_kernel(const float* __restrict__ w,
                                                   bf16* __restrict__ ew) {
    int row = blockIdx.x;
    long base = (long)row * T_;
    int tid = threadIdx.x;
    float v[8];
    float mx = -3.4e38f;
#pragma unroll
    for (int i = 0; i < 8; ++i) {
        v[i] = w[base + tid + i * 256];
        mx = fmaxf(mx, v[i]);
    }
#pragma unroll
    for (int off = 32; off > 0; off >>= 1) mx = fmaxf(mx, __shfl_down(mx, off));
    __shared__ float red[4];
    if ((tid & 63) == 0) red[tid >> 6] = mx;
    __syncthreads();
    float rmax = fmaxf(fmaxf(red[0], red[1]), fmaxf(red[2], red[3]));
#pragma unroll
    for (int i = 0; i < 8; ++i)
        ew[poff(row, tid + i * 256, T_)] = __float2bfloat16(expf(v[i] - rmax));
}

// ---------------- max over batch dim of K [B,T,D] -> [T*D] (f32) ----------------
__global__ __launch_bounds__(256) void maxk_kernel(const bf16* __restrict__ K,
                                                   float* __restrict__ mk) {
    long i = (long)blockIdx.x * 256 + threadIdx.x;
    float m = ldf(K, i);
#pragma unroll
    for (int b = 1; b < B_; ++b) m = fmaxf(m, ldf(K, (long)b * (T_ * D_) + i));
    mk[i] = m;
}

// ------- build kv2T[b][n][t] PACKED (K=T_): n<512: expK*V; n>=512: expK ----------
__global__ __launch_bounds__(256) void kv2t_kernel(const bf16* __restrict__ K_,
                                                   const bf16* __restrict__ V_,
                                                   const float* __restrict__ mk,
                                                   bf16* __restrict__ kv2t) {
    __shared__ float sev[64][65];
    __shared__ float se[64][65];
    int tx = threadIdx.x & 63, ty = threadIdx.x >> 6;
    int t0 = blockIdx.x * 64, d0 = blockIdx.y * 64, b = blockIdx.z;
    long ibase = (long)b << 20;
#pragma unroll
    for (int r = 0; r < 16; ++r) {
        int tl = r * 4 + ty;
        long mi = (long)(t0 + tl) * D_ + d0 + tx;
        float e = expf(ldf(K_, ibase + mi) - mk[mi]);
        sev[tl][tx] = e * ldf(V_, ibase + mi);
        se[tl][tx] = e;
    }
    __syncthreads();
    long obase = (long)b << 21;
#pragma unroll
    for (int r = 0; r < 16; ++r) {
        int dl = r * 4 + ty;
        kv2t[obase + poff(d0 + dl, t0 + tx, T_)]       = __float2bfloat16(sev[tx][dl]);
        kv2t[obase + poff(512 + d0 + dl, t0 + tx, T_)] = __float2bfloat16(se[tx][dl]);
    }
}

// ---------------- Yt = sigQ * num/den, in place on sigQ ----------------
__global__ __launch_bounds__(256) void yt_kernel(const bf16* __restrict__ nd,
                                                 bf16* __restrict__ q) {
    long i = (long)blockIdx.x * 256 + threadIdx.x;
    long td = i & (long)(T_ * D_ - 1);
    long b = i >> 20;
    long t = td >> 9;
    long d = td & (D_ - 1);
    long base = (b << 21) + (t << 10);
    float num = ldf(nd, base + d), den = ldf(nd, base + D_ + d);
    q[i] = __float2bfloat16(ldf(q, i) * num / den);
}

// -------- batched weight transpose + f32->bf16: W[K,N] -> WT[N,K] PACKED ----------
struct WT6 {
    const float* src[6];
    bf16* dst[6];
    int K[6], N[6];
};
__global__ __launch_bounds__(256) void wtrans6_kernel(WT6 p) {
    int z = blockIdx.z;
    int K = p.K[z], N = p.N[z];
    int n0 = blockIdx.x * 64, k0 = blockIdx.y * 64;
    if (n0 >= N || k0 >= K) return;
    const float* W = p.src[z];
    bf16* WT = p.dst[z];
    __shared__ float s[64][65];
    int tx = threadIdx.x & 63, ty = threadIdx.x >> 6;
#pragma unroll
    for (int r = 0; r < 16; ++r) {
        int kl = r * 4 + ty;
        s[kl][tx] = W[(long)(k0 + kl) * N + n0 + tx];
    }
    __syncthreads();
#pragma unroll
    for (int r = 0; r < 16; ++r) {
        int nl = r * 4 + ty;
        WT[poff(n0 + nl, k0 + tx, K)] = __float2bfloat16(s[tx][nl]);
    }
}

// ---------------- MFMA GEMM: C = epi(A@Bt^T + bias) [+res] ------------------------
// 128 x 128 macro-tile, 4 waves, 2-buffer LDS, plain C++ LDS reads (compiler-managed
// lgkmcnt), __syncthreads per K-step. 4 blocks/CU (56 VGPR + 64 AGPR = 120 regs,
// 32 KB LDS). Proven R4 structure — sync/compute byte-identical here.
// pk bit0: A packed (16x32 tiles); bit1: B packed; bit2: C written packed
// (non-plane path only, res must be null). Packed staging = contiguous 1KB bursts.
// XCD swizzle: 3D chunked remap over (x,y,z) — for batched GEMMs each XCD gets one
// batch (L2 working set = its own B panel); z=1 reduces to R4's proven 2D remap.
// planeStride!=0: N split into 512-col planes; per-plane bias b0/b1/b2 and
// mode=(modes>>(2*plane))&3. mode 0=none 1=sigmoid 2=gelu.
template <int BM>
__global__ __launch_bounds__(256, 3) void mfma_gemm(
    const bf16* __restrict__ A, const bf16* __restrict__ Bt,
    const float* __restrict__ b0, const float* __restrict__ b1,
    const float* __restrict__ b2,
    bf16* __restrict__ Cb, float* __restrict__ Cf,
    const bf16* __restrict__ resb, const float* __restrict__ resf,
    int M, int N, int K, int modes, long bsB, long bsC, long planeStride, int pk) {
    constexpr int MI = BM / 32;
    constexpr int NA = BM / 64;
    constexpr int PL = (BM + 128) * 32;  // shorts per LDS buffer plane
    __shared__ short Sh[2 * PL];         // 2 bufs: 32KB @BM=128
    int tid = threadIdx.x;
    int lane = tid & 63, wave = tid >> 6;
    int wm = wave & 1, wn = wave >> 1;

    // 3D chunked XCD swizzle (nwg % 8 == 0 for every launch here)
    int gx = gridDim.x, gy = gridDim.y;
    long nwg = (long)gx * gy * gridDim.z;
    long o = blockIdx.x + (long)gx * (blockIdx.y + (long)gy * blockIdx.z);
    long wk = (o & 7) * (nwg >> 3) + (o >> 3);
    int bx = (int)(wk % gx);
    long rq = wk / gx;
    int by = (int)(rq % gy);
    int bz = (int)(rq / gy);
    int m0 = by * BM, n0 = bx * 128;

    const bool PA = pk & 1, PB = pk & 2, PCK = pk & 4;
    const short* Ag = (const short*)A;
    const short* Bg = (const short*)Bt + (long)bz * bsB;

    int lr = lane >> 2;
    int le = (lane & 3) * 8;
    const short* ga[NA];
    short* la[NA];
#pragma unroll
    for (int i = 0; i < NA; ++i) {
        int arow = m0 + wave * (BM / 4) + i * 16;
        ga[i] = PA ? Ag + (long)(arow >> 4) * ((long)K << 4) + lane * 8
                   : Ag + (long)(arow + lr) * K + le;
        la[i] = Sh + (wave * (BM / 4) + i * 16) * 32;
    }
    int brow = n0 + wave * 32;
    const short* gb0 = PB ? Bg + (long)(brow >> 4) * ((long)K << 4) + lane * 8
                          : Bg + (long)(brow + lr) * K + le;
    const short* gb1 = PB ? gb0 + ((long)K << 4) : gb0 + 16L * K;
    short* lb0 = Sh + BM * 32 + (wave * 32) * 32;
    short* lb1 = lb0 + 16 * 32;
    const long astep = PA ? 512 : 32;
    const long bstep = PB ? 512 : 32;

    f32x4 acc[MI][4];
    f32x4 zz = {0.f, 0.f, 0.f, 0.f};
#pragma unroll
    for (int i = 0; i < MI; ++i)
#pragma unroll
        for (int j = 0; j < 4; ++j) acc[i][j] = zz;

    int fr = lane & 15;
    int fk = (lane >> 4) * 8;
    int rm = wm * (BM / 2);

    auto stage = [&](int kt, int ofs) {
#pragma unroll
        for (int i = 0; i < NA; ++i) GLD16(ga[i] + kt * astep, la[i] + ofs);
        GLD16(gb0 + kt * bstep, lb0 + ofs);
        GLD16(gb1 + kt * bstep, lb1 + ofs);
    };
    auto compute = [&](int ofs) {
        const short* Asb = Sh + ofs;
        const short* Bsb = Sh + ofs + BM * 32;
        bf16x8 af[MI], bv[4];
#pragma unroll
        for (int mi = 0; mi < MI; ++mi)
            af[mi] = *(const bf16x8*)(Asb + (rm + mi * 16 + fr) * 32 + fk);
#pragma unroll
        for (int ni = 0; ni < 4; ++ni)
            bv[ni] = *(const bf16x8*)(Bsb + (wn * 64 + ni * 16 + fr) * 32 + fk);
#pragma unroll
        for (int mi = 0; mi < MI; ++mi)
#pragma unroll
            for (int ni = 0; ni < 4; ++ni)
                acc[mi][ni] = __builtin_amdgcn_mfma_f32_16x16x32_bf16(
                    af[mi], bv[ni], acc[mi][ni], 0, 0, 0);
    };

    // ---- 2-buffer pipelined K loop (nk even for all shapes used: K=512/2048) ----
    int nk = K >> 5;
    stage(0, 0);
    __syncthreads();
    for (int kt = 0; kt < nk; kt += 2) {
        if (kt + 1 < nk) stage(kt + 1, PL);
        compute(0);
        __syncthreads();
        if (kt + 2 < nk) stage(kt + 2, 0);
        compute(PL);
        __syncthreads();
    }

    int cc = lane & 15, cr = (lane >> 4) * 4;
    long cbase = (long)bz * bsC;
#pragma unroll
    for (int mi = 0; mi < MI; ++mi) {
#pragma unroll
        for (int ni = 0; ni < 4; ++ni) {
            int row0 = m0 + rm + mi * 16 + cr;
            int col = n0 + wn * 64 + ni * 16 + cc;
            float bvl;
            long colterm;
            int md, rowstride;
            if (planeStride) {
                int plane = col >> 9;
                int c2 = col & 511;
                const float* bp = (plane == 0) ? b0 : ((plane == 1) ? b1 : b2);
                bvl = bp[c2];
                md = (modes >> (2 * plane)) & 3;
                colterm = (long)plane * planeStride + c2;
                rowstride = 512;
            } else {
                bvl = b0 ? b0[col] : 0.0f;
                md = modes & 3;
                colterm = col;
                rowstride = N;
            }
#pragma unroll
            for (int r = 0; r < 4; ++r) {
                float v = acc[mi][ni][r] + bvl;
                if (md == 1) v = 1.0f / (1.0f + __expf(-v));
                else if (md == 2) v = gelu_f(v);
                long idx;
                if (PCK) idx = cbase + poff(row0 + r, col, N);
                else     idx = cbase + (long)(row0 + r) * rowstride + colterm;
                if (resf) v += resf[idx];
                if (resb) v += ldf(resb, idx);
                if (Cf) Cf[idx] = v;
                else Cb[idx] = __float2bfloat16(v);
            }
        }
    }
}

extern "C" void kernel_launch(void* const* d_in, const int* in_sizes, int n_in,
                              void* d_out, int out_size, void* d_ws, size_t ws_size,
                              hipStream_t stream) {
    const float* x    = (const float*)d_in[0];
    const float* ln1g = (const float*)d_in[1];
    const float* ln1b = (const float*)d_in[2];
    const float* Wk   = (const float*)d_in[3];
    const float* bk   = (const float*)d_in[4];
    const float* Wv   = (const float*)d_in[5];
    const float* bv   = (const float*)d_in[6];
    const float* Wq   = (const float*)d_in[7];
    const float* bq   = (const float*)d_in[8];
    const float* w    = (const float*)d_in[9];
    const float* Wo   = (const float*)d_in[10];
    const float* bo   = (const float*)d_in[11];
    const float* ln2g = (const float*)d_in[12];
    const float* ln2b = (const float*)d_in[13];
    const float* W1   = (const float*)d_in[14];
    const float* b1   = (const float*)d_in[15];
    const float* W2   = (const float*)d_in[16];
    const float* b2   = (const float*)d_in[17];
    float* out = (float*)d_out;

    const long S_BTD = (long)B_ * T_ * D_;      // 8,388,608
    const long S_TD  = (long)T_ * D_;           // 1,048,576
    const long S_TT  = (long)T_ * T_;           // 4,194,304
    const long S_B2D = (long)B_ * T_ * 2 * D_;  // 16,777,216
    const long S_DD  = (long)D_ * D_;           // 262,144

    // Workspace (bf16 elems unless noted) ~136 MB:
    bf16* h1     = (bf16*)d_ws;            // later h2 (both PACKED)
    bf16* outres = h1 + S_BTD;             // linear
    bf16* ew     = outres + S_BTD;         // PACKED
    bf16* KVQ    = ew + S_TT;              // K|V|Q planes (3*S_BTD), linear
    bf16* kv2t   = KVQ + 3 * S_BTD;        // S_B2D, PACKED per batch
    float* mk    = (float*)(kv2t + S_B2D); // S_TD f32
    bf16* WkT    = (bf16*)(mk + S_TD);     // all weights PACKED
    bf16* WvT    = WkT + S_DD;
    bf16* WqT    = WvT + S_DD;
    bf16* WoT    = WqT + S_DD;
    bf16* W1T    = WoT + S_DD;             // [H,D]
    bf16* W2T    = W1T + (long)D_ * H_;    // [D,H]
    bf16* Kb  = KVQ;
    bf16* Vb  = KVQ + S_BTD;
    bf16* Qb  = KVQ + 2 * S_BTD;           // sigQ, then Yt in place (linear)
    bf16* nd  = KVQ;                       // overwrites K|V planes after kv2t
    bf16* hH  = KVQ;                       // PACKED; spans KVQ+kv2t >= 33.6M elems
    bf16* h2  = h1;

    const int M = B_ * T_;  // 16384

    // 1. batched weight transposes (packed output)
    WT6 p;
    p.src[0] = Wk; p.src[1] = Wv; p.src[2] = Wq; p.src[3] = Wo; p.src[4] = W1; p.src[5] = W2;
    p.dst[0] = WkT; p.dst[1] = WvT; p.dst[2] = WqT; p.dst[3] = WoT; p.dst[4] = W1T; p.dst[5] = W2T;
    p.K[0] = p.K[1] = p.K[2] = p.K[3] = 512; p.K[4] = 512; p.K[5] = 2048;
    p.N[0] = p.N[1] = p.N[2] = p.N[3] = 512; p.N[4] = 2048; p.N[5] = 512;
    wtrans6_kernel<<<dim3(32, 32, 6), 256, 0, stream>>>(p);
    // 2. h1 = LN1(x), packed
    ln_kernel<float, true><<<M, 256, 0, stream>>>(x, ln1g, ln1b, h1);
    // 3. K|V|sigQ GEMM: N=1536 over [WkT;WvT;WqT] (packed concat: whole tiles)
    mfma_gemm<128><<<dim3(1536 / 128, M / 128, 1), 256, 0, stream>>>(
        h1, WkT, bk, bv, bq, Kb, nullptr, nullptr, nullptr,
        M, 1536, D_, (1 << 4), 0, 0, S_BTD, 3);
    // 4. mk = max_b K; 5. kv2t = [expK*V | expK]^T per batch (packed)
    maxk_kernel<<<S_TD / 256, 256, 0, stream>>>(Kb, mk);
    kv2t_kernel<<<dim3(T_ / 64, D_ / 64, B_), 256, 0, stream>>>(Kb, Vb, mk, kv2t);
    // 6. exp_w (packed)
    expw_kernel<<<T_, 256, 0, stream>>>(w, ew);
    // 7. nd[b] = ew @ kv2t[b]^T  (M=2048, N=1024, K=2048), A+B packed, out linear
    mfma_gemm<128><<<dim3(1024 / 128, T_ / 128, B_), 256, 0, stream>>>(
        ew, kv2t, nullptr, nullptr, nullptr, nd, nullptr, nullptr, nullptr,
        T_, 1024, T_, 0, (long)1024 * T_, (long)T_ * 1024, 0, 3);
    // 8. Yt = sigQ * num/den (in place on Qb, linear)
    yt_kernel<<<S_BTD / 256, 256, 0, stream>>>(nd, Qb);
    // 9. out = Yt@Wo + bo + x   (A linear, B packed)
    mfma_gemm<128><<<dim3(D_ / 128, M / 128, 1), 256, 0, stream>>>(
        Qb, WoT, bo, nullptr, nullptr, outres, nullptr, nullptr, x,
        M, D_, D_, 0, 0, 0, 0, 2);
    // 10. h2 = LN2(out), packed
    ln_kernel<bf16, true><<<M, 256, 0, stream>>>(outres, ln2g, ln2b, h2);
    // 11. hH = gelu(h2@W1 + b1), A+B packed, C PACKED (N=2048 == step-12 K)
    mfma_gemm<128><<<dim3(H_ / 128, M / 128, 1), 256, 0, stream>>>(
        h2, W1T, b1, nullptr, nullptr, hH, nullptr, nullptr, nullptr,
        M, H_, D_, 2, 0, 0, 0, 7);
    // 12. y = gelu(hH@W2 + b2) + out -> f32 d_out  (A packed, B packed)
    mfma_gemm<128><<<dim3(D_ / 128, M / 128, 1), 256, 0, stream>>>(
        hH, W2T, b2, nullptr, nullptr, nullptr, out, outres, nullptr,
        M, D_, H_, 2, 0, 0, 0, 3);
}

// Round 6
// 473.940 us; speedup vs baseline: 1.7253x; 1.0341x over previous
//
#include <hip/hip_runtime.h>
#include <hip/hip_bf16.h>
#include <math.h>

typedef __hip_bfloat16 bf16;
typedef __bf16 bf16x8 __attribute__((ext_vector_type(8)));
typedef float f32x4 __attribute__((ext_vector_type(4)));

#define B_ 8
#define T_ 2048
#define D_ 512
#define H_ 2048

__device__ __forceinline__ float b2f(unsigned short u) {
    return __uint_as_float((unsigned)u << 16);
}
__device__ __forceinline__ float ldf(const float* p, long i) { return p[i]; }
__device__ __forceinline__ float ldf(const bf16* p, long i) {
    return b2f(((const unsigned short*)p)[i]);
}
// tanh-form gelu: v*sigmoid(1.59577(v+0.044715 v^3)); |err| < 1e-3 abs
__device__ __forceinline__ float gelu_f(float v) {
    float a = 1.5957691216057308f * (v + 0.044715f * v * v * v);
    return v / (1.0f + __expf(-a));
}

// Packed (tile-major) layout for GEMM-staged operands:
// tile = 16 rows x 32 cols (1 KB bf16) = exactly one wave's global_load_lds
// payload in LDS dest order: within-tile offset = (row&15)*32 + (col&31).
// tiles ordered (row-tile-major, then k-tile):
//   off(row,col,K) = ((row>>4)*(K>>5) + (col>>5))*512 + (row&15)*32 + (col&31)
// => staging is fully-contiguous 1KB bursts (8 full 128B lines): FETCH 138->25MB.
__device__ __forceinline__ long poff(int row, int col, int K) {
    return ((long)(row >> 4) * (K >> 5) + (col >> 5)) * 512 + (row & 15) * 32 + (col & 31);
}

#define GLD16(g, l)                                                          \
    __builtin_amdgcn_global_load_lds(                                        \
        (const __attribute__((address_space(1))) void*)(g),                  \
        (__attribute__((address_space(3))) void*)(l), 16, 0, 0)

// ---------------- LayerNorm over D=512, one block (256 thr) per row ----------------
// PACKO: emit y in packed tile layout (consumed only by GEMM staging)
template <typename Tin, bool PACKO>
__global__ __launch_bounds__(256) void ln_kernel(const Tin* __restrict__ x,
                                                 const float* __restrict__ g,
                                                 const float* __restrict__ bb,
                                                 bf16* __restrict__ y) {
    int row = blockIdx.x;
    long base = (long)row * D_;
    int tid = threadIdx.x;
    float v0 = ldf(x, base + tid);
    float v1 = ldf(x, base + tid + 256);
    float s = v0 + v1;
#pragma unroll
    for (int off = 32; off > 0; off >>= 1) s += __shfl_down(s, off);
    __shared__ float red[4];
    int lane = tid & 63, wid = tid >> 6;
    if (lane == 0) red[wid] = s;
    __syncthreads();
    float mean = (red[0] + red[1] + red[2] + red[3]) * (1.0f / 512.0f);
    __syncthreads();
    float d0 = v0 - mean, d1 = v1 - mean;
    float vs = d0 * d0 + d1 * d1;
#pragma unroll
    for (int off = 32; off > 0; off >>= 1) vs += __shfl_down(vs, off);
    if (lane == 0) red[wid] = vs;
    __syncthreads();
    float var = (red[0] + red[1] + red[2] + red[3]) * (1.0f / 512.0f);
    float rstd = rsqrtf(var + 1e-5f);
    float o0 = d0 * rstd * g[tid] + bb[tid];
    float o1 = d1 * rstd * g[tid + 256] + bb[tid + 256];
    if (PACKO) {
        y[poff(row, tid, D_)]       = __float2bfloat16(o0);
        y[poff(row, tid + 256, D_)] = __float2bfloat16(o1);
    } else {
        y[base + tid]       = __float2bfloat16(o0);
        y[base + tid + 256] = __float2bfloat16(o1);
    }
}

// ---------------- exp(w - rowmax(w)) : one block per row; PACKED output ----------
__global__ __launch_bounds__(256) void expw_kernel(const float* __restrict__ w,
                                                   bf16* __restrict__ ew) {
    int row = blockIdx.x;
    long base = (long)row * T_;
    int tid = threadIdx.x;
    float v[8];
    float mx = -3.4e38f;
#pragma unroll
    for (int i = 0; i < 8; ++i) {
        v[i] = w[base + tid + i * 256];
        mx = fmaxf(mx, v[i]);
    }
#pragma unroll
    for (int off = 32; off > 0; off >>= 1) mx = fmaxf(mx, __shfl_down(mx, off));
    __shared__ float red[4];
    if ((tid & 63) == 0) red[tid >> 6] = mx;
    __syncthreads();
    float rmax = fmaxf(fmaxf(red[0], red[1]), fmaxf(red[2], red[3]));
#pragma unroll
    for (int i = 0; i < 8; ++i)
        ew[poff(row, tid + i * 256, T_)] = __float2bfloat16(expf(v[i] - rmax));
}

// ---------------- max over batch dim of K [B,T,D] -> [T*D] (f32) ----------------
__global__ __launch_bounds__(256) void maxk_kernel(const bf16* __restrict__ K,
                                                   float* __restrict__ mk) {
    long i = (long)blockIdx.x * 256 + threadIdx.x;
    float m = ldf(K, i);
#pragma unroll
    for (int b = 1; b < B_; ++b) m = fmaxf(m, ldf(K, (long)b * (T_ * D_) + i));
    mk[i] = m;
}

// ------- build kv2T[b][n][t] PACKED (K=T_): n<512: expK*V; n>=512: expK ----------
__global__ __launch_bounds__(256) void kv2t_kernel(const bf16* __restrict__ K_,
                                                   const bf16* __restrict__ V_,
                                                   const float* __restrict__ mk,
                                                   bf16* __restrict__ kv2t) {
    __shared__ float sev[64][65];
    __shared__ float se[64][65];
    int tx = threadIdx.x & 63, ty = threadIdx.x >> 6;
    int t0 = blockIdx.x * 64, d0 = blockIdx.y * 64, b = blockIdx.z;
    long ibase = (long)b << 20;
#pragma unroll
    for (int r = 0; r < 16; ++r) {
        int tl = r * 4 + ty;
        long mi = (long)(t0 + tl) * D_ + d0 + tx;
        float e = expf(ldf(K_, ibase + mi) - mk[mi]);
        sev[tl][tx] = e * ldf(V_, ibase + mi);
        se[tl][tx] = e;
    }
    __syncthreads();
    long obase = (long)b << 21;
#pragma unroll
    for (int r = 0; r < 16; ++r) {
        int dl = r * 4 + ty;
        kv2t[obase + poff(d0 + dl, t0 + tx, T_)]       = __float2bfloat16(sev[tx][dl]);
        kv2t[obase + poff(512 + d0 + dl, t0 + tx, T_)] = __float2bfloat16(se[tx][dl]);
    }
}

// ---------------- Yt = sigQ * num/den, in place on sigQ ----------------
__global__ __launch_bounds__(256) void yt_kernel(const bf16* __restrict__ nd,
                                                 bf16* __restrict__ q) {
    long i = (long)blockIdx.x * 256 + threadIdx.x;
    long td = i & (long)(T_ * D_ - 1);
    long b = i >> 20;
    long t = td >> 9;
    long d = td & (D_ - 1);
    long base = (b << 21) + (t << 10);
    float num = ldf(nd, base + d), den = ldf(nd, base + D_ + d);
    q[i] = __float2bfloat16(ldf(q, i) * num / den);
}

// -------- batched weight transpose + f32->bf16: W[K,N] -> WT[N,K] PACKED ----------
struct WT6 {
    const float* src[6];
    bf16* dst[6];
    int K[6], N[6];
};
__global__ __launch_bounds__(256) void wtrans6_kernel(WT6 p) {
    int z = blockIdx.z;
    int K = p.K[z], N = p.N[z];
    int n0 = blockIdx.x * 64, k0 = blockIdx.y * 64;
    if (n0 >= N || k0 >= K) return;
    const float* W = p.src[z];
    bf16* WT = p.dst[z];
    __shared__ float s[64][65];
    int tx = threadIdx.x & 63, ty = threadIdx.x >> 6;
#pragma unroll
    for (int r = 0; r < 16; ++r) {
        int kl = r * 4 + ty;
        s[kl][tx] = W[(long)(k0 + kl) * N + n0 + tx];
    }
    __syncthreads();
#pragma unroll
    for (int r = 0; r < 16; ++r) {
        int nl = r * 4 + ty;
        WT[poff(n0 + nl, k0 + tx, K)] = __float2bfloat16(s[tx][nl]);
    }
}

// ---------------- MFMA GEMM: C = epi(A@Bt^T + bias) [+res] ------------------------
// 128 x 128 macro-tile, 4 waves, 2-buffer LDS, plain C++ LDS reads (compiler-managed
// lgkmcnt), __syncthreads per K-step. R5 -> R6 deltas:
//  * __launch_bounds__(256,4): 60 VGPR + 64 AGPR = 124 <= 128 -> 4 blocks/CU
//    resident (16 waves/CU) — one more independent block to cover the per-step
//    vmcnt(0) barrier-drain stall (m114: cross-block overlap is what hides it).
//  * PK is now a template arg -> astep/bstep constexpr -> staging address math is
//    strength-reduced adds, not per-load 64-bit muls (VALUBusy was 50%).
// PK bit0: A packed (16x32 tiles); bit1: B packed; bit2: C written packed
// (non-plane path only). XCD swizzle: 3D chunked remap over (x,y,z).
// planeStride!=0: N split into 512-col planes; per-plane bias b0/b1/b2 and
// mode=(modes>>(2*plane))&3. mode 0=none 1=sigmoid 2=gelu.
template <int BM, int PK>
__global__ __launch_bounds__(256, 4) void mfma_gemm(
    const bf16* __restrict__ A, const bf16* __restrict__ Bt,
    const float* __restrict__ b0, const float* __restrict__ b1,
    const float* __restrict__ b2,
    bf16* __restrict__ Cb, float* __restrict__ Cf,
    const bf16* __restrict__ resb, const float* __restrict__ resf,
    int M, int N, int K, int modes, long bsB, long bsC, long planeStride) {
    constexpr int MI = BM / 32;
    constexpr int NA = BM / 64;
    constexpr int PL = (BM + 128) * 32;  // shorts per LDS buffer plane
    constexpr bool PA = PK & 1, PB = PK & 2, PCK = PK & 4;
    constexpr long astep = PA ? 512 : 32;
    constexpr long bstep = PB ? 512 : 32;
    __shared__ short Sh[2 * PL];         // 2 bufs: 32KB @BM=128
    int tid = threadIdx.x;
    int lane = tid & 63, wave = tid >> 6;
    int wm = wave & 1, wn = wave >> 1;

    // 3D chunked XCD swizzle (nwg % 8 == 0 for every launch here)
    int gx = gridDim.x, gy = gridDim.y;
    long nwg = (long)gx * gy * gridDim.z;
    long o = blockIdx.x + (long)gx * (blockIdx.y + (long)gy * blockIdx.z);
    long wk = (o & 7) * (nwg >> 3) + (o >> 3);
    int bx = (int)(wk % gx);
    long rq = wk / gx;
    int by = (int)(rq % gy);
    int bz = (int)(rq / gy);
    int m0 = by * BM, n0 = bx * 128;

    const short* Ag = (const short*)A;
    const short* Bg = (const short*)Bt + (long)bz * bsB;

    int lr = lane >> 2;
    int le = (lane & 3) * 8;
    const short* ga[NA];
    short* la[NA];
#pragma unroll
    for (int i = 0; i < NA; ++i) {
        int arow = m0 + wave * (BM / 4) + i * 16;
        ga[i] = PA ? Ag + (long)(arow >> 4) * ((long)K << 4) + lane * 8
                   : Ag + (long)(arow + lr) * K + le;
        la[i] = Sh + (wave * (BM / 4) + i * 16) * 32;
    }
    int brow = n0 + wave * 32;
    const short* gb0 = PB ? Bg + (long)(brow >> 4) * ((long)K << 4) + lane * 8
                          : Bg + (long)(brow + lr) * K + le;
    const short* gb1 = PB ? gb0 + ((long)K << 4) : gb0 + 16L * K;
    short* lb0 = Sh + BM * 32 + (wave * 32) * 32;
    short* lb1 = lb0 + 16 * 32;

    f32x4 acc[MI][4];
    f32x4 zz = {0.f, 0.f, 0.f, 0.f};
#pragma unroll
    for (int i = 0; i < MI; ++i)
#pragma unroll
        for (int j = 0; j < 4; ++j) acc[i][j] = zz;

    int fr = lane & 15;
    int fk = (lane >> 4) * 8;
    int rm = wm * (BM / 2);

    auto stage = [&](int kt, int ofs) {
#pragma unroll
        for (int i = 0; i < NA; ++i) GLD16(ga[i] + kt * astep, la[i] + ofs);
        GLD16(gb0 + kt * bstep, lb0 + ofs);
        GLD16(gb1 + kt * bstep, lb1 + ofs);
    };
    auto compute = [&](int ofs) {
        const short* Asb = Sh + ofs;
        const short* Bsb = Sh + ofs + BM * 32;
        bf16x8 af[MI], bv[4];
#pragma unroll
        for (int mi = 0; mi < MI; ++mi)
            af[mi] = *(const bf16x8*)(Asb + (rm + mi * 16 + fr) * 32 + fk);
#pragma unroll
        for (int ni = 0; ni < 4; ++ni)
            bv[ni] = *(const bf16x8*)(Bsb + (wn * 64 + ni * 16 + fr) * 32 + fk);
#pragma unroll
        for (int mi = 0; mi < MI; ++mi)
#pragma unroll
            for (int ni = 0; ni < 4; ++ni)
                acc[mi][ni] = __builtin_amdgcn_mfma_f32_16x16x32_bf16(
                    af[mi], bv[ni], acc[mi][ni], 0, 0, 0);
    };

    // ---- 2-buffer pipelined K loop (nk even for all shapes used: K=512/2048) ----
    int nk = K >> 5;
    stage(0, 0);
    __syncthreads();
    for (int kt = 0; kt < nk; kt += 2) {
        if (kt + 1 < nk) stage(kt + 1, PL);
        compute(0);
        __syncthreads();
        if (kt + 2 < nk) stage(kt + 2, 0);
        compute(PL);
        __syncthreads();
    }

    int cc = lane & 15, cr = (lane >> 4) * 4;
    long cbase = (long)bz * bsC;
#pragma unroll
    for (int mi = 0; mi < MI; ++mi) {
#pragma unroll
        for (int ni = 0; ni < 4; ++ni) {
            int row0 = m0 + rm + mi * 16 + cr;
            int col = n0 + wn * 64 + ni * 16 + cc;
            float bvl;
            long colterm;
            int md, rowstride;
            if (planeStride) {
                int plane = col >> 9;
                int c2 = col & 511;
                const float* bp = (plane == 0) ? b0 : ((plane == 1) ? b1 : b2);
                bvl = bp[c2];
                md = (modes >> (2 * plane)) & 3;
                colterm = (long)plane * planeStride + c2;
                rowstride = 512;
            } else {
                bvl = b0 ? b0[col] : 0.0f;
                md = modes & 3;
                colterm = col;
                rowstride = N;
            }
#pragma unroll
            for (int r = 0; r < 4; ++r) {
                float v = acc[mi][ni][r] + bvl;
                if (md == 1) v = 1.0f / (1.0f + __expf(-v));
                else if (md == 2) v = gelu_f(v);
                long idx;
                if (PCK) idx = cbase + poff(row0 + r, col, N);
                else     idx = cbase + (long)(row0 + r) * rowstride + colterm;
                if (resf) v += resf[idx];
                if (resb) v += ldf(resb, idx);
                if (Cf) Cf[idx] = v;
                else Cb[idx] = __float2bfloat16(v);
            }
        }
    }
}

extern "C" void kernel_launch(void* const* d_in, const int* in_sizes, int n_in,
                              void* d_out, int out_size, void* d_ws, size_t ws_size,
                              hipStream_t stream) {
    const float* x    = (const float*)d_in[0];
    const float* ln1g = (const float*)d_in[1];
    const float* ln1b = (const float*)d_in[2];
    const float* Wk   = (const float*)d_in[3];
    const float* bk   = (const float*)d_in[4];
    const float* Wv   = (const float*)d_in[5];
    const float* bv   = (const float*)d_in[6];
    const float* Wq   = (const float*)d_in[7];
    const float* bq   = (const float*)d_in[8];
    const float* w    = (const float*)d_in[9];
    const float* Wo   = (const float*)d_in[10];
    const float* bo   = (const float*)d_in[11];
    const float* ln2g = (const float*)d_in[12];
    const float* ln2b = (const float*)d_in[13];
    const float* W1   = (const float*)d_in[14];
    const float* b1   = (const float*)d_in[15];
    const float* W2   = (const float*)d_in[16];
    const float* b2   = (const float*)d_in[17];
    float* out = (float*)d_out;

    const long S_BTD = (long)B_ * T_ * D_;      // 8,388,608
    const long S_TD  = (long)T_ * D_;           // 1,048,576
    const long S_TT  = (long)T_ * T_;           // 4,194,304
    const long S_B2D = (long)B_ * T_ * 2 * D_;  // 16,777,216
    const long S_DD  = (long)D_ * D_;           // 262,144

    // Workspace (bf16 elems unless noted) ~136 MB:
    bf16* h1     = (bf16*)d_ws;            // later h2 (both PACKED)
    bf16* outres = h1 + S_BTD;             // linear
    bf16* ew     = outres + S_BTD;         // PACKED
    bf16* KVQ    = ew + S_TT;              // K|V|Q planes (3*S_BTD), linear
    bf16* kv2t   = KVQ + 3 * S_BTD;        // S_B2D, PACKED per batch
    float* mk    = (float*)(kv2t + S_B2D); // S_TD f32
    bf16* WkT    = (bf16*)(mk + S_TD);     // all weights PACKED
    bf16* WvT    = WkT + S_DD;
    bf16* WqT    = WvT + S_DD;
    bf16* WoT    = WqT + S_DD;
    bf16* W1T    = WoT + S_DD;             // [H,D]
    bf16* W2T    = W1T + (long)D_ * H_;    // [D,H]
    bf16* Kb  = KVQ;
    bf16* Vb  = KVQ + S_BTD;
    bf16* Qb  = KVQ + 2 * S_BTD;           // sigQ, then Yt in place (linear)
    bf16* nd  = KVQ;                       // overwrites K|V planes after kv2t
    bf16* hH  = KVQ;                       // PACKED; spans KVQ+kv2t >= 33.6M elems
    bf16* h2  = h1;

    const int M = B_ * T_;  // 16384

    // 1. batched weight transposes (packed output)
    WT6 p;
    p.src[0] = Wk; p.src[1] = Wv; p.src[2] = Wq; p.src[3] = Wo; p.src[4] = W1; p.src[5] = W2;
    p.dst[0] = WkT; p.dst[1] = WvT; p.dst[2] = WqT; p.dst[3] = WoT; p.dst[4] = W1T; p.dst[5] = W2T;
    p.K[0] = p.K[1] = p.K[2] = p.K[3] = 512; p.K[4] = 512; p.K[5] = 2048;
    p.N[0] = p.N[1] = p.N[2] = p.N[3] = 512; p.N[4] = 2048; p.N[5] = 512;
    wtrans6_kernel<<<dim3(32, 32, 6), 256, 0, stream>>>(p);
    // 2. h1 = LN1(x), packed
    ln_kernel<float, true><<<M, 256, 0, stream>>>(x, ln1g, ln1b, h1);
    // 3. K|V|sigQ GEMM: N=1536 over [WkT;WvT;WqT] (packed concat: whole tiles)
    mfma_gemm<128, 3><<<dim3(1536 / 128, M / 128, 1), 256, 0, stream>>>(
        h1, WkT, bk, bv, bq, Kb, nullptr, nullptr, nullptr,
        M, 1536, D_, (1 << 4), 0, 0, S_BTD);
    // 4. mk = max_b K; 5. kv2t = [expK*V | expK]^T per batch (packed)
    maxk_kernel<<<S_TD / 256, 256, 0, stream>>>(Kb, mk);
    kv2t_kernel<<<dim3(T_ / 64, D_ / 64, B_), 256, 0, stream>>>(Kb, Vb, mk, kv2t);
    // 6. exp_w (packed)
    expw_kernel<<<T_, 256, 0, stream>>>(w, ew);
    // 7. nd[b] = ew @ kv2t[b]^T  (M=2048, N=1024, K=2048), A+B packed, out linear
    mfma_gemm<128, 3><<<dim3(1024 / 128, T_ / 128, B_), 256, 0, stream>>>(
        ew, kv2t, nullptr, nullptr, nullptr, nd, nullptr, nullptr, nullptr,
        T_, 1024, T_, 0, (long)1024 * T_, (long)T_ * 1024, 0);
    // 8. Yt = sigQ * num/den (in place on Qb, linear)
    yt_kernel<<<S_BTD / 256, 256, 0, stream>>>(nd, Qb);
    // 9. out = Yt@Wo + bo + x   (A linear, B packed)
    mfma_gemm<128, 2><<<dim3(D_ / 128, M / 128, 1), 256, 0, stream>>>(
        Qb, WoT, bo, nullptr, nullptr, outres, nullptr, nullptr, x,
        M, D_, D_, 0, 0, 0, 0);
    // 10. h2 = LN2(out), packed
    ln_kernel<bf16, true><<<M, 256, 0, stream>>>(outres, ln2g, ln2b, h2);
    // 11. hH = gelu(h2@W1 + b1), A+B packed, C PACKED (N=2048 == step-12 K)
    mfma_gemm<128, 7><<<dim3(H_ / 128, M / 128, 1), 256, 0, stream>>>(
        h2, W1T, b1, nullptr, nullptr, hH, nullptr, nullptr, nullptr,
        M, H_, D_, 2, 0, 0, 0);
    // 12. y = gelu(hH@W2 + b2) + out -> f32 d_out  (A packed, B packed)
    mfma_gemm<128, 3><<<dim3(D_ / 128, M / 128, 1), 256, 0, stream>>>(
        hH, W2T, b2, nullptr, nullptr, nullptr, out, outres, nullptr,
        M, D_, H_, 2, 0, 0, 0);
}